// Round 1
// baseline (374.922 us; speedup 1.0000x reference)
//
#include <hip/hip_runtime.h>

typedef unsigned short u16;
typedef __attribute__((ext_vector_type(8))) short bf16x8;
typedef __attribute__((ext_vector_type(4))) float f32x4;

#define LOG2E 1.4426950408889634f

__device__ __forceinline__ u16 f2b_bits(float f) {
  unsigned u = __builtin_bit_cast(unsigned, f);
  return (u16)((u + 0x7fffu + ((u >> 16) & 1u)) >> 16);  // RN-even
}
__device__ __forceinline__ float b2f(u16 b) {
  unsigned u = ((unsigned)b) << 16;
  return __builtin_bit_cast(float, u);
}

// inv_freq[i] = 10000^(-i/12) = 10^(-i/3)
__device__ __constant__ float INVF[12] = {
  1.0f, 0.46415888336127786f, 0.21544346900318834f, 0.1f,
  0.04641588833612779f, 0.021544346900318832f, 0.01f, 0.004641588833612779f,
  0.0021544346900318843f, 0.001f, 0.00046415888336127786f, 0.00021544346900318823f
};

// ---------------- convert: fp32 -> bf16 for x and the 4 weight matrices ----
__global__ void __launch_bounds__(256) convert_kernel(
    const float* __restrict__ x, const float* __restrict__ wq,
    const float* __restrict__ wk, const float* __restrict__ wv,
    const float* __restrict__ wo,
    u16* __restrict__ xb, u16* __restrict__ wqb, u16* __restrict__ wkb,
    u16* __restrict__ wvb, u16* __restrict__ wob) {
  int idx = blockIdx.x * 256 + threadIdx.x;            // one float4 per thread
  const int CX = 1179648, CW = 331776;                 // 4718592/4, 1327104/4
  if (idx >= CX + 4 * CW) return;
  const float4* src; u16* dst; int off;
  if (idx < CX)            { src = (const float4*)x;  dst = xb;  off = idx; }
  else if (idx < CX +   CW){ src = (const float4*)wq; dst = wqb; off = idx - CX; }
  else if (idx < CX + 2*CW){ src = (const float4*)wk; dst = wkb; off = idx - CX - CW; }
  else if (idx < CX + 3*CW){ src = (const float4*)wv; dst = wvb; off = idx - CX - 2*CW; }
  else                     { src = (const float4*)wo; dst = wob; off = idx - CX - 3*CW; }
  float4 v = src[off];
  ushort4 o;
  o.x = f2b_bits(v.x); o.y = f2b_bits(v.y); o.z = f2b_bits(v.z); o.w = f2b_bits(v.w);
  *(ushort4*)(dst + (size_t)off * 4) = o;
}

// ---------------- 128x128 bf16 GEMM, C[m,n] = sum_k A[m,k]*W[n,k] + bias[n] --
// MODE 0: QKV (bf16 out to qkv[4096][3456], W/bias selected per n-section)
// MODE 1: out-proj (f32 out to d_out[4096][1152])
template <int MODE>
__global__ void __launch_bounds__(256) gemm_kernel(
    const u16* __restrict__ A, const u16* __restrict__ W0,
    const u16* __restrict__ W1, const u16* __restrict__ W2,
    const float* __restrict__ b0, const float* __restrict__ b1,
    const float* __restrict__ b2, u16* __restrict__ Cb, float* __restrict__ Cf,
    int nTN) {
  __shared__ u16 As[128][40];   // pad 32->40: frag reads ~2-way conflict (free)
  __shared__ u16 Bs[128][40];
  const int K = 1152;
  int bm = blockIdx.x / nTN, bn = blockIdx.x % nTN;
  int m0 = bm * 128;
  const u16* W; const float* bias; int nsec, nn0;
  if constexpr (MODE == 0) {
    nsec = bn / 9; nn0 = (bn % 9) * 128;
    W    = (nsec == 0) ? W0 : (nsec == 1) ? W1 : W2;
    bias = (nsec == 0) ? b0 : (nsec == 1) ? b1 : b2;
  } else {
    nsec = 0; nn0 = bn * 128; W = W0; bias = b0;
  }
  int tid = threadIdx.x, lane = tid & 63, wid = tid >> 6;
  int lr = lane & 15, lg = lane >> 4;
  int wr = wid >> 1, wc = wid & 1;

  // staging: thread handles rows tid>>2 and 64+(tid>>2), col-chunk (tid&3)*8
  const u16* gA0 = A + (size_t)(m0 + (tid >> 2)) * K + (tid & 3) * 8;
  const u16* gA1 = gA0 + (size_t)64 * K;
  const u16* gB0 = W + (size_t)(nn0 + (tid >> 2)) * K + (tid & 3) * 8;
  const u16* gB1 = gB0 + (size_t)64 * K;
  u16* sA0 = &As[tid >> 2][(tid & 3) * 8];
  u16* sA1 = &As[64 + (tid >> 2)][(tid & 3) * 8];
  u16* sB0 = &Bs[tid >> 2][(tid & 3) * 8];
  u16* sB1 = &Bs[64 + (tid >> 2)][(tid & 3) * 8];

  f32x4 acc[4][4];
#pragma unroll
  for (int m = 0; m < 4; ++m)
#pragma unroll
    for (int n = 0; n < 4; ++n) acc[m][n] = (f32x4){0.f, 0.f, 0.f, 0.f};

  for (int k0 = 0; k0 < K; k0 += 32) {
    __syncthreads();
    *(bf16x8*)sA0 = *(const bf16x8*)gA0;
    *(bf16x8*)sA1 = *(const bf16x8*)gA1;
    *(bf16x8*)sB0 = *(const bf16x8*)gB0;
    *(bf16x8*)sB1 = *(const bf16x8*)gB1;
    gA0 += 32; gA1 += 32; gB0 += 32; gB1 += 32;
    __syncthreads();
    bf16x8 af[4], bf[4];
#pragma unroll
    for (int m = 0; m < 4; ++m)
      af[m] = *(const bf16x8*)&As[wr * 64 + m * 16 + lr][lg * 8];
#pragma unroll
    for (int n = 0; n < 4; ++n)
      bf[n] = *(const bf16x8*)&Bs[wc * 64 + n * 16 + lr][lg * 8];
#pragma unroll
    for (int m = 0; m < 4; ++m)
#pragma unroll
      for (int n = 0; n < 4; ++n)
        acc[m][n] = __builtin_amdgcn_mfma_f32_16x16x32_bf16(af[m], bf[n], acc[m][n], 0, 0, 0);
  }

#pragma unroll
  for (int n = 0; n < 4; ++n) {
    int col = nn0 + wc * 64 + n * 16 + lr;
    float bv = bias[col];
#pragma unroll
    for (int m = 0; m < 4; ++m) {
#pragma unroll
      for (int j = 0; j < 4; ++j) {
        int row = m0 + wr * 64 + m * 16 + lg * 4 + j;
        float v = acc[m][n][j] + bv;
        if constexpr (MODE == 0)
          Cb[(size_t)row * 3456 + nsec * 1152 + col] = f2b_bits(v);
        else
          Cf[(size_t)row * 1152 + col] = v;
      }
    }
  }
}

// ---------------- RoPE (q scaled by 1/sqrt(72)) + head layout [BH][S][96] ---
__global__ void __launch_bounds__(256) rope_kernel(
    const u16* __restrict__ qkv, u16* __restrict__ Qr, u16* __restrict__ Kr) {
  int idx = blockIdx.x * 256 + threadIdx.x;  // total 32*2048*48
  if (idx >= 32 * 2048 * 48) return;
  int p = idx % 48;
  int rest = idx / 48;
  int s = rest & 2047;
  int bh = rest >> 11;
  int b = bh >> 4, h = bh & 15;
  u16* qo = Qr + ((size_t)bh * 2048 + s) * 96;
  u16* ko = Kr + ((size_t)bh * 2048 + s) * 96;
  if (p >= 36) {  // zero the pad cols [72,96)
    int d = 72 + (p - 36);
    qo[d] = 0; qo[d + 12] = 0; ko[d] = 0; ko[d + 12] = 0;
    return;
  }
  int a = p / 12, f = p % 12;
  int dlo = a * 24 + f, dhi = dlo + 12;
  int pos = (a == 0) ? (s >> 8) : (a == 1) ? ((s >> 4) & 15) : (s & 15);
  float fr = (float)pos * INVF[f];
  float sn, cs;
  __sincosf(fr, &sn, &cs);
  const u16* row = qkv + (size_t)(b * 2048 + s) * 3456 + h * 72;
  float q1 = b2f(row[dlo]), q2 = b2f(row[dhi]);
  float k1 = b2f(row[1152 + dlo]), k2 = b2f(row[1152 + dhi]);
  const float sc = 0.11785113019775793f;  // 1/sqrt(72)
  qo[dlo] = f2b_bits((q1 * cs - q2 * sn) * sc);
  qo[dhi] = f2b_bits((q2 * cs + q1 * sn) * sc);
  ko[dlo] = f2b_bits(k1 * cs - k2 * sn);
  ko[dhi] = f2b_bits(k2 * cs + k1 * sn);
}

// ---------------- V transpose: qkv v-part -> Vt[BH][80][2048] (rows 72..79=0)
__global__ void __launch_bounds__(256) vtrans_kernel(
    const u16* __restrict__ qkv, u16* __restrict__ Vt) {
  int idx = blockIdx.x * 256 + threadIdx.x;  // total 32*80*512
  if (idx >= 32 * 80 * 512) return;
  int s4 = idx & 511;
  int rest = idx >> 9;
  int d = rest % 80;
  int bh = rest / 80;
  int b = bh >> 4, h = bh & 15;
  ushort4 v;
  if (d < 72) {
    const u16* src = qkv + (size_t)(b * 2048 + s4 * 4) * 3456 + 2304 + h * 72 + d;
    v.x = src[0]; v.y = src[3456]; v.z = src[2 * 3456]; v.w = src[3 * 3456];
  } else {
    v = make_ushort4(0, 0, 0, 0);
  }
  *(ushort4*)(Vt + (size_t)bh * 80 * 2048 + (size_t)d * 2048 + s4 * 4) = v;
}

// ---------------- flash attention -------------------------------------------
// grid: 32 bh * 32 q-tiles(64 rows). 4 waves x 16 q-rows. KT=128 keys/iter.
__global__ void __launch_bounds__(256) attn_kernel(
    const u16* __restrict__ Qr, const u16* __restrict__ Kr,
    const u16* __restrict__ Vt, u16* __restrict__ AO) {
  __shared__ u16 Ks[128][104];        // 96 + 8 pad (2-way bank, free)
  __shared__ u16 Vsf[80 * 128];       // XOR-swizzled rows
  __shared__ u16 Ps[4][16][136];      // per-wave P tile, padded
  int bh = blockIdx.x >> 5;
  int q0 = (blockIdx.x & 31) * 64;
  int tid = threadIdx.x, lane = tid & 63, wid = tid >> 6;
  int lr = lane & 15, lg = lane >> 4;
  const u16* Qh = Qr + (size_t)bh * 2048 * 96;
  const u16* Kh = Kr + (size_t)bh * 2048 * 96;
  const u16* Vh = Vt + (size_t)bh * 80 * 2048;

  bf16x8 qf[3];
#pragma unroll
  for (int kc = 0; kc < 3; ++kc)
    qf[kc] = *(const bf16x8*)(Qh + (size_t)(q0 + wid * 16 + lr) * 96 + kc * 32 + lg * 8);

  f32x4 Oacc[5];
#pragma unroll
  for (int of = 0; of < 5; ++of) Oacc[of] = (f32x4){0.f, 0.f, 0.f, 0.f};
  float mrow[4] = {-1e30f, -1e30f, -1e30f, -1e30f};
  float lrow[4] = {0.f, 0.f, 0.f, 0.f};

  // staging address precompute
  const u16* gK[6]; u16* sK[6];
#pragma unroll
  for (int i = 0; i < 6; ++i) {       // 128 rows x 12 chunks of 8
    int c = i * 256 + tid;
    int row = c / 12, c8 = c - row * 12;
    gK[i] = Kh + (size_t)row * 96 + c8 * 8;
    sK[i] = &Ks[row][c8 * 8];
  }
  const u16* gV[5]; u16* sV[5];
#pragma unroll
  for (int i = 0; i < 5; ++i) {       // 80 rows x 16 chunks of 8
    int c = i * 256 + tid;
    int d = c >> 4, c8 = c & 15;
    gV[i] = Vh + (size_t)d * 2048 + c8 * 8;
    int byt = (d * 256 + c8 * 16) ^ ((d & 7) << 4);
    sV[i] = (u16*)((char*)Vsf + byt);
  }

  for (int kt = 0; kt < 2048; kt += 128) {
    __syncthreads();
#pragma unroll
    for (int i = 0; i < 6; ++i)
      *(bf16x8*)sK[i] = *(const bf16x8*)(gK[i] + (size_t)kt * 96);
#pragma unroll
    for (int i = 0; i < 5; ++i)
      *(bf16x8*)sV[i] = *(const bf16x8*)(gV[i] + kt);
    __syncthreads();

    // QK^T : scores [16 rows][128 cols] per wave
    f32x4 scf[8];
#pragma unroll
    for (int cf = 0; cf < 8; ++cf) {
      f32x4 s = (f32x4){0.f, 0.f, 0.f, 0.f};
#pragma unroll
      for (int kc = 0; kc < 3; ++kc) {
        bf16x8 kf = *(const bf16x8*)&Ks[cf * 16 + lr][kc * 32 + lg * 8];
        s = __builtin_amdgcn_mfma_f32_16x16x32_bf16(qf[kc], kf, s, 0, 0, 0);
      }
      scf[cf] = s;
    }

    // online softmax (rows = lg*4+j, reduce over 16 lanes sharing lg)
    float corr[4], rsum[4];
#pragma unroll
    for (int j = 0; j < 4; ++j) {
      float t = scf[0][j];
#pragma unroll
      for (int cf = 1; cf < 8; ++cf) t = fmaxf(t, scf[cf][j]);
#pragma unroll
      for (int off = 8; off >= 1; off >>= 1) t = fmaxf(t, __shfl_xor(t, off));
      float mn = fmaxf(mrow[j], t);
      corr[j] = exp2f((mrow[j] - mn) * LOG2E);
      mrow[j] = mn;
      rsum[j] = 0.f;
    }
#pragma unroll
    for (int cf = 0; cf < 8; ++cf)
#pragma unroll
      for (int j = 0; j < 4; ++j) {
        float pv = exp2f((scf[cf][j] - mrow[j]) * LOG2E);
        scf[cf][j] = pv;
        rsum[j] += pv;
      }
#pragma unroll
    for (int j = 0; j < 4; ++j) {
#pragma unroll
      for (int off = 8; off >= 1; off >>= 1) rsum[j] += __shfl_xor(rsum[j], off);
      lrow[j] = lrow[j] * corr[j] + rsum[j];
    }
#pragma unroll
    for (int of = 0; of < 5; ++of)
#pragma unroll
      for (int j = 0; j < 4; ++j) Oacc[of][j] *= corr[j];

    // P -> LDS (bf16)
#pragma unroll
    for (int cf = 0; cf < 8; ++cf)
#pragma unroll
      for (int j = 0; j < 4; ++j)
        Ps[wid][lg * 4 + j][cf * 16 + lr] = f2b_bits(scf[cf][j]);
    __syncthreads();

    // PV : O += P @ V^T
#pragma unroll
    for (int s4 = 0; s4 < 4; ++s4) {
      bf16x8 pf = *(const bf16x8*)&Ps[wid][lr][s4 * 32 + lg * 8];
#pragma unroll
      for (int of = 0; of < 5; ++of) {
        int vrow = of * 16 + lr;
        int vbyte = (vrow * 256 + s4 * 64 + lg * 16) ^ ((vrow & 7) << 4);
        bf16x8 vf = *(const bf16x8*)((const char*)Vsf + vbyte);
        Oacc[of] = __builtin_amdgcn_mfma_f32_16x16x32_bf16(pf, vf, Oacc[of], 0, 0, 0);
      }
    }
  }

  int b = bh >> 4, h = bh & 15;
  float invl[4];
#pragma unroll
  for (int j = 0; j < 4; ++j) invl[j] = 1.0f / lrow[j];
#pragma unroll
  for (int of = 0; of < 5; ++of) {
    int d = of * 16 + lr;
    if (d < 72) {
#pragma unroll
      for (int j = 0; j < 4; ++j) {
        int srow = q0 + wid * 16 + lg * 4 + j;
        AO[(size_t)(b * 2048 + srow) * 1152 + h * 72 + d] =
            f2b_bits(Oacc[of][j] * invl[j]);
      }
    }
  }
}

// ---------------- launch -----------------------------------------------------
extern "C" void kernel_launch(void* const* d_in, const int* in_sizes, int n_in,
                              void* d_out, int out_size, void* d_ws, size_t ws_size,
                              hipStream_t stream) {
  const float* hs = (const float*)d_in[0];
  const float* Wq = (const float*)d_in[1];
  const float* bq = (const float*)d_in[2];
  const float* Wk = (const float*)d_in[3];
  const float* bk = (const float*)d_in[4];
  const float* Wv = (const float*)d_in[5];
  const float* bv = (const float*)d_in[6];
  const float* Wo = (const float*)d_in[7];
  const float* bo = (const float*)d_in[8];
  float* out = (float*)d_out;

  char* w = (char*)d_ws;
  u16* xb  = (u16*)w; w += 9437184;    // x bf16 [4096][1152]; later reused as AO
  u16* wqb = (u16*)w; w += 2654208;
  u16* wkb = (u16*)w; w += 2654208;
  u16* wvb = (u16*)w; w += 2654208;
  u16* wob = (u16*)w; w += 2654208;
  u16* qkv = (u16*)w; w += 28311552;   // [4096][3456]
  u16* Qr  = (u16*)w; w += 12582912;   // [32][2048][96]
  u16* Kr  = (u16*)w; w += 12582912;
  u16* Vt  = (u16*)w; w += 10485760;   // [32][80][2048]
  u16* AO  = xb;                       // attn out [4096][1152], aliases xb

  convert_kernel<<<9792, 256, 0, stream>>>(hs, Wq, Wk, Wv, Wo, xb, wqb, wkb, wvb, wob);
  gemm_kernel<0><<<864, 256, 0, stream>>>(xb, wqb, wkb, wvb, bq, bk, bv, qkv, nullptr, 27);
  rope_kernel<<<12288, 256, 0, stream>>>(qkv, Qr, Kr);
  vtrans_kernel<<<5120, 256, 0, stream>>>(qkv, Vt);
  attn_kernel<<<1024, 256, 0, stream>>>(Qr, Kr, Vt, AO);
  gemm_kernel<1><<<288, 256, 0, stream>>>(AO, wob, nullptr, nullptr, bo, nullptr, nullptr,
                                          nullptr, out, 9);
}

// Round 3
// 344.357 us; speedup vs baseline: 1.0888x; 1.0888x over previous
//
#include <hip/hip_runtime.h>

typedef unsigned short u16;
typedef unsigned int u32;
typedef __attribute__((ext_vector_type(8))) short bf16x8;
typedef __attribute__((ext_vector_type(4))) float f32x4;

#define SCQ 0.17002324f  /* (1/sqrt(72)) * log2(e): QK^T scores land in log2 domain */

__device__ __forceinline__ u16 f2b_bits(float f) {
  unsigned u = __builtin_bit_cast(unsigned, f);
  return (u16)((u + 0x7fffu + ((u >> 16) & 1u)) >> 16);  // RN-even
}
__device__ __forceinline__ float b2f(u16 b) {
  unsigned u = ((unsigned)b) << 16;
  return __builtin_bit_cast(float, u);
}
__device__ __forceinline__ u32 cvt_pk_bf16(float lo, float hi) {
  u32 r;
  asm("v_cvt_pk_bf16_f32 %0, %1, %2" : "=v"(r) : "v"(lo), "v"(hi));
  return r;
}
typedef __attribute__((address_space(1))) const void gvoid;
typedef __attribute__((address_space(3))) void lvoid;
__device__ __forceinline__ void load_lds16(const void* g, void* l) {
  __builtin_amdgcn_global_load_lds((gvoid*)g, (lvoid*)l, 16, 0, 0);
}

// inv_freq[i] = 10000^(-i/12) = 10^(-i/3)
__device__ __constant__ float INVF[12] = {
  1.0f, 0.46415888336127786f, 0.21544346900318834f, 0.1f,
  0.04641588833612779f, 0.021544346900318832f, 0.01f, 0.004641588833612779f,
  0.0021544346900318843f, 0.001f, 0.00046415888336127786f, 0.00021544346900318823f
};

// ---------------- convert: fp32 -> bf16 for x and the 4 weight matrices ----
__global__ void __launch_bounds__(256) convert_kernel(
    const float* __restrict__ x, const float* __restrict__ wq,
    const float* __restrict__ wk, const float* __restrict__ wv,
    const float* __restrict__ wo,
    u16* __restrict__ xb, u16* __restrict__ wqb, u16* __restrict__ wkb,
    u16* __restrict__ wvb, u16* __restrict__ wob) {
  int idx = blockIdx.x * 256 + threadIdx.x;            // one float4 per thread
  const int CX = 1179648, CW = 331776;                 // 4718592/4, 1327104/4
  if (idx >= CX + 4 * CW) return;
  const float4* src; u16* dst; int off;
  if (idx < CX)            { src = (const float4*)x;  dst = xb;  off = idx; }
  else if (idx < CX +   CW){ src = (const float4*)wq; dst = wqb; off = idx - CX; }
  else if (idx < CX + 2*CW){ src = (const float4*)wk; dst = wkb; off = idx - CX - CW; }
  else if (idx < CX + 3*CW){ src = (const float4*)wv; dst = wvb; off = idx - CX - 2*CW; }
  else                     { src = (const float4*)wo; dst = wob; off = idx - CX - 3*CW; }
  float4 v = src[off];
  ushort4 o;
  o.x = f2b_bits(v.x); o.y = f2b_bits(v.y); o.z = f2b_bits(v.z); o.w = f2b_bits(v.w);
  *(ushort4*)(dst + (size_t)off * 4) = o;
}

// ---------------- 128x128 bf16 GEMM (m97 structure: global_load_lds 16B) ----
// C[m,n] = sum_k A[m,k]*W[n,k] + bias[n]
// LDS linear [128][32] u16; XOR swizzle: LDS[row][c8] holds global[row][c8 ^ (row>>1 & 3)]
// (applied by pre-swizzling the per-lane GLOBAL source; frag reads use same XOR).
template <int MODE>
__global__ void __launch_bounds__(256) gemm_kernel(
    const u16* __restrict__ A, const u16* __restrict__ W0,
    const u16* __restrict__ W1, const u16* __restrict__ W2,
    const float* __restrict__ b0, const float* __restrict__ b1,
    const float* __restrict__ b2, u16* __restrict__ Cb, float* __restrict__ Cf,
    int nTN) {
  __shared__ __align__(16) u16 As[128 * 32];
  __shared__ __align__(16) u16 Bs[128 * 32];
  const int K = 1152;
  int nWG = gridDim.x;                      // % 8 == 0 for all our launches
  int bid = blockIdx.x;
  int wg = (bid & 7) * (nWG >> 3) + (bid >> 3);   // bijective XCD swizzle
  int bm = wg / nTN, bn = wg % nTN;
  int m0 = bm * 128;
  const u16* W; const float* bias; int nsec, nn0;
  if constexpr (MODE == 0) {
    nsec = bn / 9; nn0 = (bn % 9) * 128;
    W    = (nsec == 0) ? W0 : (nsec == 1) ? W1 : W2;
    bias = (nsec == 0) ? b0 : (nsec == 1) ? b1 : b2;
  } else {
    nsec = 0; nn0 = bn * 128; W = W0; bias = b0;
  }
  int tid = threadIdx.x, lane = tid & 63, wid = tid >> 6;
  int lr = lane & 15, lg = lane >> 4;
  int wr = wid >> 1, wc = wid & 1;

  // staging: thread tid fills LDS bytes [tid*16, +16) (and +4096 for 2nd half)
  int srow = tid >> 2;                                   // 0..63
  int scol = ((tid & 3) ^ ((tid >> 3) & 3)) << 3;        // pre-swizzled src col
  const u16* gA = A + (size_t)(m0 + srow) * K + scol;
  const u16* gB = W + (size_t)(nn0 + srow) * K + scol;
  u16* lA = As + wid * 512;                              // wave-uniform LDS base
  u16* lB = Bs + wid * 512;
  // frag read col (u16): same XOR, constant per thread
  int fcol = (lg ^ ((lr >> 1) & 3)) << 3;

  f32x4 acc[4][4];
#pragma unroll
  for (int m = 0; m < 4; ++m)
#pragma unroll
    for (int n = 0; n < 4; ++n) acc[m][n] = (f32x4){0.f, 0.f, 0.f, 0.f};

  for (int k0 = 0; k0 < K; k0 += 32) {
    __syncthreads();
    load_lds16(gA, lA);
    load_lds16(gA + (size_t)64 * K, lA + 2048);
    load_lds16(gB, lB);
    load_lds16(gB + (size_t)64 * K, lB + 2048);
    gA += 32; gB += 32;
    __syncthreads();   // drains vmcnt -> LDS tiles ready
    bf16x8 af[4], bf[4];
#pragma unroll
    for (int m = 0; m < 4; ++m)
      af[m] = *(const bf16x8*)&As[(wr * 64 + m * 16 + lr) * 32 + fcol];
#pragma unroll
    for (int n = 0; n < 4; ++n)
      bf[n] = *(const bf16x8*)&Bs[(wc * 64 + n * 16 + lr) * 32 + fcol];
#pragma unroll
    for (int m = 0; m < 4; ++m)
#pragma unroll
      for (int n = 0; n < 4; ++n)
        acc[m][n] = __builtin_amdgcn_mfma_f32_16x16x32_bf16(af[m], bf[n], acc[m][n], 0, 0, 0);
  }

#pragma unroll
  for (int n = 0; n < 4; ++n) {
    int col = nn0 + wc * 64 + n * 16 + lr;
    float bv = bias[col];
#pragma unroll
    for (int m = 0; m < 4; ++m) {
#pragma unroll
      for (int j = 0; j < 4; ++j) {
        int row = m0 + wr * 64 + m * 16 + lg * 4 + j;
        float v = acc[m][n][j] + bv;
        if constexpr (MODE == 0)
          Cb[(size_t)row * 3456 + nsec * 1152 + col] = f2b_bits(v);
        else
          Cf[(size_t)row * 1152 + col] = v;
      }
    }
  }
}

// ---------------- RoPE via LDS table; one row (q or k of one s) per thread --
// axis-chunked (24 elems live at a time) to keep VGPR pressure low
__global__ void __launch_bounds__(256) rope_kernel(
    const u16* __restrict__ qkv, u16* __restrict__ Qr, u16* __restrict__ Kr) {
  __shared__ float csT[480], snT[480];
  int tid = threadIdx.x;
  for (int t = tid; t < 480; t += 256) {
    int a = t < 96 ? 0 : (t < 288 ? 1 : 2);
    int rel = t - (a == 0 ? 0 : (a == 1 ? 96 : 288));
    int pos = rel / 12, f = rel % 12;
    float ang = (float)pos * INVF[f];
    csT[t] = __cosf(ang);
    snT[t] = __sinf(ang);
  }
  __syncthreads();
  int bh = blockIdx.x >> 4;                 // 32 bh x 16 s-tiles of 128
  int s0 = (blockIdx.x & 15) * 128;
  int b = bh >> 4, h = bh & 15;
  int sl = tid >> 1, isk = tid & 1;
  int s = s0 + sl;
  const u16* src = qkv + (size_t)(b * 2048 + s) * 3456 + isk * 1152 + h * 72;
  u16* dst = (isk ? Kr : Qr) + ((size_t)bh * 2048 + s) * 96;
  int p0 = (s >> 8) * 12, p1 = 96 + ((s >> 4) & 15) * 12, p2 = 288 + (s & 15) * 12;
  int pb[3] = {p0, p1, p2};
  float sc = isk ? 1.0f : SCQ;
#pragma unroll
  for (int a = 0; a < 3; ++a) {
    u16 x[24], o[24];
    *(bf16x8*)&x[0]  = *(const bf16x8*)&src[a * 24];
    *(bf16x8*)&x[8]  = *(const bf16x8*)&src[a * 24 + 8];
    *(bf16x8*)&x[16] = *(const bf16x8*)&src[a * 24 + 16];
#pragma unroll
    for (int f = 0; f < 12; ++f) {
      float c = csT[pb[a] + f], sn = snT[pb[a] + f];
      float x1 = b2f(x[f]), x2 = b2f(x[f + 12]);
      o[f]      = f2b_bits((x1 * c - x2 * sn) * sc);
      o[f + 12] = f2b_bits((x2 * c + x1 * sn) * sc);
    }
    *(bf16x8*)&dst[a * 24]      = *(const bf16x8*)&o[0];
    *(bf16x8*)&dst[a * 24 + 8]  = *(const bf16x8*)&o[8];
    *(bf16x8*)&dst[a * 24 + 16] = *(const bf16x8*)&o[16];
  }
  bf16x8 z = (bf16x8){0, 0, 0, 0, 0, 0, 0, 0};
  *(bf16x8*)&dst[72] = z;
  *(bf16x8*)&dst[80] = z;
  *(bf16x8*)&dst[88] = z;
}

// ---------------- V transpose via LDS tile (coalesced both sides) -----------
__global__ void __launch_bounds__(256) vtrans_kernel(
    const u16* __restrict__ qkv, u16* __restrict__ Vt) {
  __shared__ u16 T[72][137];                // odd pad
  int bh = blockIdx.x >> 4;                 // 32 bh x 16 s-tiles of 128
  int s0 = (blockIdx.x & 15) * 128;
  int b = bh >> 4, h = bh & 15;
  int tid = threadIdx.x;
  for (int c = tid; c < 1152; c += 256) {   // 128 s-rows x 9 chunks of 8
    int sl = c / 9, c8 = c % 9;
    bf16x8 v = *(const bf16x8*)(qkv + (size_t)(b * 2048 + s0 + sl) * 3456 + 2304 + h * 72 + c8 * 8);
#pragma unroll
    for (int i = 0; i < 8; ++i) T[c8 * 8 + i][sl] = (u16)v[i];
  }
  __syncthreads();
  for (int j = tid; j < 1280; j += 256) {   // 80 d-rows x 16 chunks of 8
    int d = j >> 4, sc = j & 15;
    bf16x8 o;
#pragma unroll
    for (int i = 0; i < 8; ++i) o[i] = (d < 72) ? (short)T[d][sc * 8 + i] : (short)0;
    *(bf16x8*)(Vt + (size_t)bh * 80 * 2048 + (size_t)d * 2048 + s0 + sc * 8) = o;
  }
}

// ---------------- flash attention (KT=64, 32.8KB LDS -> 4 blocks/CU) --------
__global__ void __launch_bounds__(256, 4) attn_kernel(
    const u16* __restrict__ Qr, const u16* __restrict__ Kr,
    const u16* __restrict__ Vt, u16* __restrict__ AO) {
  __shared__ __align__(16) u16 Ks[64][104];   // 13312 B (208B stride: 52 banks, odd-ish)
  __shared__ __align__(16) u16 Vsf[80 * 64];  // 10240 B, XOR-swizzled 128B rows
  __shared__ __align__(16) u16 Ps[4][16][72]; //  9216 B per-wave P tile
  int bid = blockIdx.x;
  int wg = (bid & 7) * 128 + (bid >> 3);      // XCD swizzle: 4 bh per XCD
  int bh = wg >> 5;
  int q0 = (wg & 31) * 64;
  int tid = threadIdx.x, lane = tid & 63, wid = tid >> 6;
  int lr = lane & 15, lg = lane >> 4;
  const u16* Qh = Qr + (size_t)bh * 2048 * 96;
  const u16* Kh = Kr + (size_t)bh * 2048 * 96;
  const u16* Vh = Vt + (size_t)bh * 80 * 2048;

  bf16x8 qf[3];
#pragma unroll
  for (int kc = 0; kc < 3; ++kc)
    qf[kc] = *(const bf16x8*)(Qh + (size_t)(q0 + wid * 16 + lr) * 96 + kc * 32 + lg * 8);

  f32x4 Oacc[5];
#pragma unroll
  for (int of = 0; of < 5; ++of) Oacc[of] = (f32x4){0.f, 0.f, 0.f, 0.f};
  float mrow[4] = {-1e30f, -1e30f, -1e30f, -1e30f};
  float lrow[4] = {0.f, 0.f, 0.f, 0.f};

  // K staging: 64 rows x 12 chunks = 768 = 3/thread
  const u16* gK[3]; u16* sK[3];
#pragma unroll
  for (int i = 0; i < 3; ++i) {
    int c = i * 256 + tid;
    int row = c / 12, c8 = c % 12;
    gK[i] = Kh + (size_t)row * 96 + c8 * 8;
    sK[i] = &Ks[row][c8 * 8];
  }

  for (int kt = 0; kt < 2048; kt += 64) {
    __syncthreads();
#pragma unroll
    for (int i = 0; i < 3; ++i)
      *(bf16x8*)sK[i] = *(const bf16x8*)(gK[i] + (size_t)kt * 96);
    for (int c = tid; c < 640; c += 256) {  // 80 d x 8 chunks
      int d = c >> 3, c8 = c & 7;
      int byt = (d * 128 + c8 * 16) ^ ((d & 7) << 4);
      *(bf16x8*)((char*)Vsf + byt) = *(const bf16x8*)(Vh + (size_t)d * 2048 + kt + c8 * 8);
    }
    __syncthreads();

    // QK^T : scores [16 q-rows][64 k-cols] per wave (log2 domain via SCQ)
    f32x4 scf[4];
#pragma unroll
    for (int cf = 0; cf < 4; ++cf) {
      f32x4 s = (f32x4){0.f, 0.f, 0.f, 0.f};
#pragma unroll
      for (int kc = 0; kc < 3; ++kc) {
        bf16x8 kf = *(const bf16x8*)&Ks[cf * 16 + lr][kc * 32 + lg * 8];
        s = __builtin_amdgcn_mfma_f32_16x16x32_bf16(qf[kc], kf, s, 0, 0, 0);
      }
      scf[cf] = s;
    }

    // online softmax, rows = lg*4+j; reduce over 16 lanes sharing lg
    float tmax[4];
#pragma unroll
    for (int j = 0; j < 4; ++j) {
      float t = fmaxf(fmaxf(scf[0][j], scf[1][j]), fmaxf(scf[2][j], scf[3][j]));
#pragma unroll
      for (int off = 8; off >= 1; off >>= 1) t = fmaxf(t, __shfl_xor(t, off));
      tmax[j] = t;
    }
    // defer-max: rescale only if some row grew by > 8 (log2 units)
    bool grow = (tmax[0] > mrow[0] + 8.f) || (tmax[1] > mrow[1] + 8.f) ||
                (tmax[2] > mrow[2] + 8.f) || (tmax[3] > mrow[3] + 8.f);
    if (__any(grow)) {
#pragma unroll
      for (int j = 0; j < 4; ++j) {
        float mn = fmaxf(mrow[j], tmax[j]);
        float corr = exp2f(mrow[j] - mn);
        mrow[j] = mn;
        lrow[j] *= corr;
#pragma unroll
        for (int of = 0; of < 5; ++of) Oacc[of][j] *= corr;
      }
    }
    float rsum[4] = {0.f, 0.f, 0.f, 0.f};
#pragma unroll
    for (int cf = 0; cf < 4; ++cf)
#pragma unroll
      for (int j = 0; j < 4; ++j) {
        float pv = exp2f(scf[cf][j] - mrow[j]);
        scf[cf][j] = pv;
        rsum[j] += pv;
      }
#pragma unroll
    for (int j = 0; j < 4; ++j) {
#pragma unroll
      for (int off = 8; off >= 1; off >>= 1) rsum[j] += __shfl_xor(rsum[j], off);
      lrow[j] += rsum[j];
    }

    // P -> LDS bf16 via v_cvt_pk (wave-private tile: no barrier needed)
#pragma unroll
    for (int cf = 0; cf < 4; ++cf) {
      u32 r01 = cvt_pk_bf16(scf[cf][0], scf[cf][1]);
      u32 r23 = cvt_pk_bf16(scf[cf][2], scf[cf][3]);
      int col = cf * 16 + lr;
      Ps[wid][lg * 4 + 0][col] = (u16)r01;
      Ps[wid][lg * 4 + 1][col] = (u16)(r01 >> 16);
      Ps[wid][lg * 4 + 2][col] = (u16)r23;
      Ps[wid][lg * 4 + 3][col] = (u16)(r23 >> 16);
    }

    // PV : O += P @ V^T
#pragma unroll
    for (int s4 = 0; s4 < 2; ++s4) {
      bf16x8 pf = *(const bf16x8*)&Ps[wid][lr][s4 * 32 + lg * 8];
#pragma unroll
      for (int of = 0; of < 5; ++of) {
        int vrow = of * 16 + lr;
        int vbyte = (vrow * 128 + s4 * 64 + lg * 16) ^ ((vrow & 7) << 4);
        bf16x8 vf = *(const bf16x8*)((const char*)Vsf + vbyte);
        Oacc[of] = __builtin_amdgcn_mfma_f32_16x16x32_bf16(pf, vf, Oacc[of], 0, 0, 0);
      }
    }
  }

  int b = bh >> 4, h = bh & 15;
  float invl[4];
#pragma unroll
  for (int j = 0; j < 4; ++j) invl[j] = 1.0f / lrow[j];
#pragma unroll
  for (int of = 0; of < 5; ++of) {
    int d = of * 16 + lr;
    if (d < 72) {
#pragma unroll
      for (int j = 0; j < 4; ++j) {
        int srow = q0 + wid * 16 + lg * 4 + j;
        AO[(size_t)(b * 2048 + srow) * 1152 + h * 72 + d] =
            f2b_bits(Oacc[of][j] * invl[j]);
      }
    }
  }
}

// ---------------- launch -----------------------------------------------------
extern "C" void kernel_launch(void* const* d_in, const int* in_sizes, int n_in,
                              void* d_out, int out_size, void* d_ws, size_t ws_size,
                              hipStream_t stream) {
  const float* hs = (const float*)d_in[0];
  const float* Wq = (const float*)d_in[1];
  const float* bq = (const float*)d_in[2];
  const float* Wk = (const float*)d_in[3];
  const float* bk = (const float*)d_in[4];
  const float* Wv = (const float*)d_in[5];
  const float* bv = (const float*)d_in[6];
  const float* Wo = (const float*)d_in[7];
  const float* bo = (const float*)d_in[8];
  float* out = (float*)d_out;

  char* w = (char*)d_ws;
  u16* xb  = (u16*)w; w += 9437184;    // x bf16 [4096][1152]; later reused as AO
  u16* wqb = (u16*)w; w += 2654208;
  u16* wkb = (u16*)w; w += 2654208;
  u16* wvb = (u16*)w; w += 2654208;
  u16* wob = (u16*)w; w += 2654208;
  u16* qkv = (u16*)w; w += 28311552;   // [4096][3456]
  u16* Qr  = (u16*)w; w += 12582912;   // [32][2048][96]
  u16* Kr  = (u16*)w; w += 12582912;
  u16* Vt  = (u16*)w; w += 10485760;   // [32][80][2048]
  u16* AO  = xb;                       // attn out [4096][1152], aliases xb

  convert_kernel<<<9792, 256, 0, stream>>>(hs, Wq, Wk, Wv, Wo, xb, wqb, wkb, wvb, wob);
  gemm_kernel<0><<<864, 256, 0, stream>>>(xb, wqb, wkb, wvb, bq, bk, bv, qkv, nullptr, 27);
  rope_kernel<<<512, 256, 0, stream>>>(qkv, Qr, Kr);
  vtrans_kernel<<<512, 256, 0, stream>>>(qkv, Vt);
  attn_kernel<<<1024, 256, 0, stream>>>(Qr, Kr, Vt, AO);
  gemm_kernel<1><<<288, 256, 0, stream>>>(AO, wob, nullptr, nullptr, bo, nullptr, nullptr,
                                          nullptr, out, 9);
}

// Round 4
// 265.396 us; speedup vs baseline: 1.4127x; 1.2975x over previous
//
#include <hip/hip_runtime.h>

typedef unsigned short u16;
typedef unsigned int u32;
typedef __attribute__((ext_vector_type(8))) short bf16x8;
typedef __attribute__((ext_vector_type(4))) short bf16x4;
typedef __attribute__((ext_vector_type(4))) float f32x4;

#define SCQ 0.17002324f  /* (1/sqrt(72)) * log2(e): QK^T scores land in log2 domain */

__device__ __forceinline__ u16 f2b_bits(float f) {
  unsigned u = __builtin_bit_cast(unsigned, f);
  return (u16)((u + 0x7fffu + ((u >> 16) & 1u)) >> 16);  // RN-even
}
__device__ __forceinline__ float b2f(u16 b) {
  unsigned u = ((unsigned)b) << 16;
  return __builtin_bit_cast(float, u);
}
__device__ __forceinline__ u32 cvt_pk_bf16(float lo, float hi) {
  u32 r;
  asm("v_cvt_pk_bf16_f32 %0, %1, %2" : "=v"(r) : "v"(lo), "v"(hi));
  return r;
}
__device__ __forceinline__ bf16x4 pack4(float a, float b, float c, float d) {
  union { u32 w[2]; bf16x4 v; } u;
  u.w[0] = cvt_pk_bf16(a, b);
  u.w[1] = cvt_pk_bf16(c, d);
  return u.v;
}
__device__ __forceinline__ f32x4 mfma16(bf16x4 a, bf16x4 b, f32x4 c) {
#if __has_builtin(__builtin_amdgcn_mfma_f32_16x16x16bf16_1k)
  return __builtin_amdgcn_mfma_f32_16x16x16bf16_1k(a, b, c, 0, 0, 0);
#else
  asm volatile("s_nop 1\nv_mfma_f32_16x16x16_bf16 %0, %1, %2, %0\ns_nop 3"
               : "+v"(c) : "v"(a), "v"(b));
  return c;
#endif
}
typedef __attribute__((address_space(1))) const void gvoid;
typedef __attribute__((address_space(3))) void lvoid;
__device__ __forceinline__ void load_lds16(const void* g, void* l) {
  __builtin_amdgcn_global_load_lds((gvoid*)g, (lvoid*)l, 16, 0, 0);
}

// inv_freq[i] = 10000^(-i/12) = 10^(-i/3)
__device__ __constant__ float INVF[12] = {
  1.0f, 0.46415888336127786f, 0.21544346900318834f, 0.1f,
  0.04641588833612779f, 0.021544346900318832f, 0.01f, 0.004641588833612779f,
  0.0021544346900318843f, 0.001f, 0.00046415888336127786f, 0.00021544346900318823f
};

// ---------------- convert: fp32 -> bf16 for x and the 4 weight matrices ----
__global__ void __launch_bounds__(256) convert_kernel(
    const float* __restrict__ x, const float* __restrict__ wq,
    const float* __restrict__ wk, const float* __restrict__ wv,
    const float* __restrict__ wo,
    u16* __restrict__ xb, u16* __restrict__ wqb, u16* __restrict__ wkb,
    u16* __restrict__ wvb, u16* __restrict__ wob) {
  int idx = blockIdx.x * 256 + threadIdx.x;            // one float4 per thread
  const int CX = 1179648, CW = 331776;                 // 4718592/4, 1327104/4
  if (idx >= CX + 4 * CW) return;
  const float4* src; u16* dst; int off;
  if (idx < CX)            { src = (const float4*)x;  dst = xb;  off = idx; }
  else if (idx < CX +   CW){ src = (const float4*)wq; dst = wqb; off = idx - CX; }
  else if (idx < CX + 2*CW){ src = (const float4*)wk; dst = wkb; off = idx - CX - CW; }
  else if (idx < CX + 3*CW){ src = (const float4*)wv; dst = wvb; off = idx - CX - 2*CW; }
  else                     { src = (const float4*)wo; dst = wob; off = idx - CX - 3*CW; }
  float4 v = src[off];
  ushort4 o;
  o.x = f2b_bits(v.x); o.y = f2b_bits(v.y); o.z = f2b_bits(v.z); o.w = f2b_bits(v.w);
  *(ushort4*)(dst + (size_t)off * 4) = o;
}

// ---------------- 128x128 bf16 GEMM, 2-phase double-buffered ---------------
// C[m,n] = sum_k A[m,k]*W[n,k] + bias[n]
// LDS [128][32] u16 linear; XOR swizzle on 8-u16 chunks by row bits 1-2,
// applied by pre-swizzling the per-lane GLOBAL source (rule 21).
template <int MODE>
__global__ void __launch_bounds__(256) gemm_kernel(
    const u16* __restrict__ A, const u16* __restrict__ W0,
    const u16* __restrict__ W1, const u16* __restrict__ W2,
    const float* __restrict__ b0, const float* __restrict__ b1,
    const float* __restrict__ b2, u16* __restrict__ Cb, float* __restrict__ Cf,
    int nTN) {
  __shared__ __align__(16) u16 As0[128 * 32];
  __shared__ __align__(16) u16 Bs0[128 * 32];
  __shared__ __align__(16) u16 As1[128 * 32];
  __shared__ __align__(16) u16 Bs1[128 * 32];
  const int K = 1152;
  int nWG = gridDim.x;                      // % 8 == 0 for all our launches
  int bid = blockIdx.x;
  int wg = (bid & 7) * (nWG >> 3) + (bid >> 3);   // bijective XCD swizzle
  int bm = wg / nTN, bn = wg % nTN;
  int m0 = bm * 128;
  const u16* W; const float* bias; int nsec, nn0;
  if constexpr (MODE == 0) {
    nsec = bn / 9; nn0 = (bn % 9) * 128;
    W    = (nsec == 0) ? W0 : (nsec == 1) ? W1 : W2;
    bias = (nsec == 0) ? b0 : (nsec == 1) ? b1 : b2;
  } else {
    nsec = 0; nn0 = bn * 128; W = W0; bias = b0;
  }
  int tid = threadIdx.x, lane = tid & 63, wid = tid >> 6;
  int lr = lane & 15, lg = lane >> 4;
  int wr = wid >> 1, wc = wid & 1;

  // staging: thread tid fills LDS bytes [tid*16, +16) (and +4096 for 2nd half)
  int srow = tid >> 2;                                   // 0..63
  int scol = ((tid & 3) ^ ((tid >> 3) & 3)) << 3;        // pre-swizzled src col
  const u16* gA = A + (size_t)(m0 + srow) * K + scol;
  const u16* gB = W + (size_t)(nn0 + srow) * K + scol;
  int lOff = wid * 512;                                  // wave-uniform LDS base
  // frag read col (u16): same XOR, constant per thread
  int fcol = (lg ^ ((lr >> 1) & 3)) << 3;

  f32x4 acc[4][4];
#pragma unroll
  for (int m = 0; m < 4; ++m)
#pragma unroll
    for (int n = 0; n < 4; ++n) acc[m][n] = (f32x4){0.f, 0.f, 0.f, 0.f};

  auto stage = [&](u16* Ad, u16* Bd, int kk) {
    load_lds16(gA + kk, Ad + lOff);
    load_lds16(gA + kk + (size_t)64 * K, Ad + lOff + 2048);
    load_lds16(gB + kk, Bd + lOff);
    load_lds16(gB + kk + (size_t)64 * K, Bd + lOff + 2048);
  };
  auto compute = [&](const u16* Asrc, const u16* Bsrc) {
    bf16x8 af[4], bf[4];
#pragma unroll
    for (int m = 0; m < 4; ++m)
      af[m] = *(const bf16x8*)&Asrc[(wr * 64 + m * 16 + lr) * 32 + fcol];
#pragma unroll
    for (int n = 0; n < 4; ++n)
      bf[n] = *(const bf16x8*)&Bsrc[(wc * 64 + n * 16 + lr) * 32 + fcol];
#pragma unroll
    for (int m = 0; m < 4; ++m)
#pragma unroll
      for (int n = 0; n < 4; ++n)
        acc[m][n] = __builtin_amdgcn_mfma_f32_16x16x32_bf16(af[m], bf[n], acc[m][n], 0, 0, 0);
  };

  stage(As0, Bs0, 0);
  __syncthreads();
  for (int k0 = 0; k0 < K; k0 += 64) {
    stage(As1, Bs1, k0 + 32);       // in flight during compute below
    compute(As0, Bs0);
    __syncthreads();
    if (k0 + 64 < K) stage(As0, Bs0, k0 + 64);
    compute(As1, Bs1);
    __syncthreads();
  }

#pragma unroll
  for (int n = 0; n < 4; ++n) {
    int col = nn0 + wc * 64 + n * 16 + lr;
    float bv = bias[col];
#pragma unroll
    for (int m = 0; m < 4; ++m) {
#pragma unroll
      for (int j = 0; j < 4; ++j) {
        int row = m0 + wr * 64 + m * 16 + lg * 4 + j;
        float v = acc[m][n][j] + bv;
        if constexpr (MODE == 0)
          Cb[(size_t)row * 3456 + nsec * 1152 + col] = f2b_bits(v);
        else
          Cf[(size_t)row * 1152 + col] = v;
      }
    }
  }
}

// ---------------- RoPE via LDS table; rows at stride 80 (72 data + 8 zero) --
__global__ void __launch_bounds__(256) rope_kernel(
    const u16* __restrict__ qkv, u16* __restrict__ Qr, u16* __restrict__ Kr) {
  __shared__ float csT[480], snT[480];
  int tid = threadIdx.x;
  for (int t = tid; t < 480; t += 256) {
    int a = t < 96 ? 0 : (t < 288 ? 1 : 2);
    int rel = t - (a == 0 ? 0 : (a == 1 ? 96 : 288));
    int pos = rel / 12, f = rel % 12;
    float ang = (float)pos * INVF[f];
    csT[t] = __cosf(ang);
    snT[t] = __sinf(ang);
  }
  __syncthreads();
  int bh = blockIdx.x >> 4;                 // 32 bh x 16 s-tiles of 128
  int s0 = (blockIdx.x & 15) * 128;
  int b = bh >> 4, h = bh & 15;
  int sl = tid >> 1, isk = tid & 1;
  int s = s0 + sl;
  const u16* src = qkv + (size_t)(b * 2048 + s) * 3456 + isk * 1152 + h * 72;
  u16* dst = (isk ? Kr : Qr) + ((size_t)bh * 2048 + s) * 80;
  int p0 = (s >> 8) * 12, p1 = 96 + ((s >> 4) & 15) * 12, p2 = 288 + (s & 15) * 12;
  int pb[3] = {p0, p1, p2};
  float sc = isk ? 1.0f : SCQ;
#pragma unroll
  for (int a = 0; a < 3; ++a) {
    u16 x[24], o[24];
    *(bf16x8*)&x[0]  = *(const bf16x8*)&src[a * 24];
    *(bf16x8*)&x[8]  = *(const bf16x8*)&src[a * 24 + 8];
    *(bf16x8*)&x[16] = *(const bf16x8*)&src[a * 24 + 16];
#pragma unroll
    for (int f = 0; f < 12; ++f) {
      float c = csT[pb[a] + f], sn = snT[pb[a] + f];
      float x1 = b2f(x[f]), x2 = b2f(x[f + 12]);
      o[f]      = f2b_bits((x1 * c - x2 * sn) * sc);
      o[f + 12] = f2b_bits((x2 * c + x1 * sn) * sc);
    }
    *(bf16x8*)&dst[a * 24]      = *(const bf16x8*)&o[0];
    *(bf16x8*)&dst[a * 24 + 8]  = *(const bf16x8*)&o[8];
    *(bf16x8*)&dst[a * 24 + 16] = *(const bf16x8*)&o[16];
  }
  bf16x8 z = (bf16x8){0, 0, 0, 0, 0, 0, 0, 0};
  *(bf16x8*)&dst[72] = z;
}

// ---------------- V transpose via LDS tile (coalesced both sides) -----------
__global__ void __launch_bounds__(256) vtrans_kernel(
    const u16* __restrict__ qkv, u16* __restrict__ Vt) {
  __shared__ u16 T[72][137];                // odd pad
  int bh = blockIdx.x >> 4;                 // 32 bh x 16 s-tiles of 128
  int s0 = (blockIdx.x & 15) * 128;
  int b = bh >> 4, h = bh & 15;
  int tid = threadIdx.x;
  for (int c = tid; c < 1152; c += 256) {   // 128 s-rows x 9 chunks of 8
    int sl = c / 9, c8 = c % 9;
    bf16x8 v = *(const bf16x8*)(qkv + (size_t)(b * 2048 + s0 + sl) * 3456 + 2304 + h * 72 + c8 * 8);
#pragma unroll
    for (int i = 0; i < 8; ++i) T[c8 * 8 + i][sl] = (u16)v[i];
  }
  __syncthreads();
  for (int j = tid; j < 1280; j += 256) {   // 80 d-rows x 16 chunks of 8
    int d = j >> 4, sc = j & 15;
    bf16x8 o;
#pragma unroll
    for (int i = 0; i < 8; ++i) o[i] = (d < 72) ? (short)T[d][sc * 8 + i] : (short)0;
    *(bf16x8*)(Vt + (size_t)bh * 80 * 2048 + (size_t)d * 2048 + s0 + sc * 8) = o;
  }
}

// ---------------- flash attention ------------------------------------------
// grid 512 = 32 bh x 16 q-tiles(128 rows); 4 waves x 32 q-rows; KVBLK=64.
// Swapped QK^T: scf = mfma(K, Q) -> lane holds P[k=16cf+4lg+j][q=lr],
// which IS the A-fragment of v_mfma 16x16x16 -> PV needs no LDS/cross-lane.
__global__ void __launch_bounds__(256, 2) attn_kernel(
    const u16* __restrict__ Qr, const u16* __restrict__ Kr,
    const u16* __restrict__ Vt, u16* __restrict__ AO) {
  __shared__ __align__(16) u16 Ks[64][88];    // 80 data + 8 pad (176B: 2-way banks)
  __shared__ __align__(16) u16 Vsf[80 * 64];  // XOR-swizzled 128B rows
  char* VsfB = (char*)Vsf;
  int bid = blockIdx.x;
  int wg = (bid & 7) * 64 + (bid >> 3);       // XCD swizzle: 4 bh per XCD
  int bh = wg >> 4;
  int q0 = (wg & 15) * 128;
  int tid = threadIdx.x, lane = tid & 63, wid = tid >> 6;
  int lr = lane & 15, lg = lane >> 4;
  const u16* Qh = Qr + (size_t)bh * 2048 * 80;
  const u16* Kh = Kr + (size_t)bh * 2048 * 80;
  const u16* Vh = Vt + (size_t)bh * 80 * 2048;

  // Q fragments (B-operand): 2 q-subtiles of 16 rows
  bf16x8 qA0[2], qA1[2]; bf16x4 qA2[2];
#pragma unroll
  for (int qs = 0; qs < 2; ++qs) {
    const u16* qrow = Qh + (size_t)(q0 + wid * 32 + qs * 16 + lr) * 80;
    qA0[qs] = *(const bf16x8*)(qrow + lg * 8);
    qA1[qs] = *(const bf16x8*)(qrow + 32 + lg * 8);
    qA2[qs] = *(const bf16x4*)(qrow + 64 + lg * 4);
  }

  f32x4 Oa0[5], Oa1[5];
#pragma unroll
  for (int of = 0; of < 5; ++of) {
    Oa0[of] = (f32x4){0.f, 0.f, 0.f, 0.f};
    Oa1[of] = (f32x4){0.f, 0.f, 0.f, 0.f};
  }
  float m0 = -1e30f, m1 = -1e30f, l0 = 0.f, l1 = 0.f;

  // staging addresses: K = 64 rows x 10 chunks (640), V = 80 rows x 8 chunks (640)
  int ck0 = tid, ck1 = 256 + tid, ck2 = 512 + tid;      // ck2 only tid<128
  int kr0 = ck0 / 10, kc0 = ck0 % 10;
  int kr1 = ck1 / 10, kc1 = ck1 % 10;
  int kr2 = ck2 / 10, kc2 = ck2 % 10;
  const u16* gK0 = Kh + (size_t)kr0 * 80 + kc0 * 8;
  const u16* gK1 = Kh + (size_t)kr1 * 80 + kc1 * 8;
  const u16* gK2 = Kh + (size_t)kr2 * 80 + kc2 * 8;
  u16* sK0 = &Ks[kr0][kc0 * 8];
  u16* sK1 = &Ks[kr1][kc1 * 8];
  u16* sK2 = &Ks[kr2][kc2 * 8];
  int vd0 = tid >> 3, vc0 = tid & 7;
  int vd1 = (256 + tid) >> 3, vc1 = tid & 7;
  int vd2 = (512 + tid) >> 3, vc2 = tid & 7;
  const u16* gV0 = Vh + (size_t)vd0 * 2048 + vc0 * 8;
  const u16* gV1 = Vh + (size_t)vd1 * 2048 + vc1 * 8;
  const u16* gV2 = Vh + (size_t)vd2 * 2048 + vc2 * 8;
  char* sV0 = VsfB + ((vd0 * 128 + vc0 * 16) ^ ((vd0 & 7) << 4));
  char* sV1 = VsfB + ((vd1 * 128 + vc1 * 16) ^ ((vd1 & 7) << 4));
  char* sV2 = VsfB + ((vd2 * 128 + vc2 * 16) ^ ((vd2 & 7) << 4));
  bool half = tid < 128;

  bf16x8 kg0, kg1, kg2, vg0, vg1, vg2;
  // T14: issue tile-0 loads now; write to LDS inside the loop after barrier
  kg0 = *(const bf16x8*)gK0;
  kg1 = *(const bf16x8*)gK1;
  if (half) kg2 = *(const bf16x8*)gK2;
  vg0 = *(const bf16x8*)gV0;
  vg1 = *(const bf16x8*)gV1;
  if (half) vg2 = *(const bf16x8*)gV2;

  for (int kt = 0; kt < 2048; kt += 64) {
    __syncthreads();                 // prev-iter LDS reads done
    *(bf16x8*)sK0 = kg0;
    *(bf16x8*)sK1 = kg1;
    if (half) *(bf16x8*)sK2 = kg2;
    *(bf16x8*)sV0 = vg0;
    *(bf16x8*)sV1 = vg1;
    if (half) *(bf16x8*)sV2 = vg2;
    __syncthreads();                 // tile visible
    if (kt + 64 < 2048) {            // T14: next tile's loads fly under compute
      size_t ko = (size_t)(kt + 64) * 80;
      kg0 = *(const bf16x8*)(gK0 + ko);
      kg1 = *(const bf16x8*)(gK1 + ko);
      if (half) kg2 = *(const bf16x8*)(gK2 + ko);
      vg0 = *(const bf16x8*)(gV0 + kt + 64);
      vg1 = *(const bf16x8*)(gV1 + kt + 64);
      if (half) vg2 = *(const bf16x8*)(gV2 + kt + 64);
    }

    // QK^T swapped: scf[qs][cf][j] = P[k=16cf+4lg+j][q=lr] (log2 domain)
    f32x4 sc0[4], sc1[4];
#pragma unroll
    for (int cf = 0; cf < 4; ++cf) {
      const u16* krow = &Ks[cf * 16 + lr][0];
      bf16x8 kf0 = *(const bf16x8*)(krow + lg * 8);
      bf16x8 kf1 = *(const bf16x8*)(krow + 32 + lg * 8);
      bf16x4 kf2 = *(const bf16x4*)(krow + 64 + lg * 4);
      f32x4 s = (f32x4){0.f, 0.f, 0.f, 0.f};
      s = __builtin_amdgcn_mfma_f32_16x16x32_bf16(kf0, qA0[0], s, 0, 0, 0);
      s = __builtin_amdgcn_mfma_f32_16x16x32_bf16(kf1, qA1[0], s, 0, 0, 0);
      sc0[cf] = mfma16(kf2, qA2[0], s);
      s = (f32x4){0.f, 0.f, 0.f, 0.f};
      s = __builtin_amdgcn_mfma_f32_16x16x32_bf16(kf0, qA0[1], s, 0, 0, 0);
      s = __builtin_amdgcn_mfma_f32_16x16x32_bf16(kf1, qA1[1], s, 0, 0, 0);
      sc1[cf] = mfma16(kf2, qA2[1], s);
    }

    // online softmax: per-lane row q=lr, k partitioned over registers + lg
    float t0 = sc0[0][0], t1 = sc1[0][0];
#pragma unroll
    for (int cf = 0; cf < 4; ++cf)
#pragma unroll
      for (int j = 0; j < 4; ++j) {
        t0 = fmaxf(t0, sc0[cf][j]);
        t1 = fmaxf(t1, sc1[cf][j]);
      }
    t0 = fmaxf(t0, __shfl_xor(t0, 16)); t0 = fmaxf(t0, __shfl_xor(t0, 32));
    t1 = fmaxf(t1, __shfl_xor(t1, 16)); t1 = fmaxf(t1, __shfl_xor(t1, 32));
    // defer-max: rescale only when a row grows by >8 (log2 units)
    bool grow = (t0 > m0 + 8.f) || (t1 > m1 + 8.f);
    if (__any(grow)) {
      float n0 = fmaxf(m0, t0), n1 = fmaxf(m1, t1);
      float c0 = __builtin_amdgcn_exp2f(m0 - n0);
      float c1 = __builtin_amdgcn_exp2f(m1 - n1);
      m0 = n0; m1 = n1; l0 *= c0; l1 *= c1;
#pragma unroll
      for (int j = 0; j < 4; ++j) {
        float r0 = __shfl(c0, lg * 4 + j);
        float r1 = __shfl(c1, lg * 4 + j);
#pragma unroll
        for (int of = 0; of < 5; ++of) { Oa0[of][j] *= r0; Oa1[of][j] *= r1; }
      }
    }
    float rs0 = 0.f, rs1 = 0.f;
    bf16x4 pa0[4], pa1[4];
#pragma unroll
    for (int cf = 0; cf < 4; ++cf) {
      float p00 = __builtin_amdgcn_exp2f(sc0[cf][0] - m0);
      float p01 = __builtin_amdgcn_exp2f(sc0[cf][1] - m0);
      float p02 = __builtin_amdgcn_exp2f(sc0[cf][2] - m0);
      float p03 = __builtin_amdgcn_exp2f(sc0[cf][3] - m0);
      rs0 += (p00 + p01) + (p02 + p03);
      pa0[cf] = pack4(p00, p01, p02, p03);
      float p10 = __builtin_amdgcn_exp2f(sc1[cf][0] - m1);
      float p11 = __builtin_amdgcn_exp2f(sc1[cf][1] - m1);
      float p12 = __builtin_amdgcn_exp2f(sc1[cf][2] - m1);
      float p13 = __builtin_amdgcn_exp2f(sc1[cf][3] - m1);
      rs1 += (p10 + p11) + (p12 + p13);
      pa1[cf] = pack4(p10, p11, p12, p13);
    }
    rs0 += __shfl_xor(rs0, 16); rs0 += __shfl_xor(rs0, 32); l0 += rs0;
    rs1 += __shfl_xor(rs1, 16); rs1 += __shfl_xor(rs1, 32); l1 += rs1;

    // PV: Oacc[q][d] += P @ V^T via 16x16x16 (A=pa direct from registers)
#pragma unroll
    for (int cf = 0; cf < 4; ++cf) {
      int coff = (32 * cf + 8 * lg) ^ ((lr & 7) << 4);
#pragma unroll
      for (int of = 0; of < 5; ++of) {
        bf16x4 vf = *(const bf16x4*)(VsfB + ((of * 16 + lr) * 128 + coff));
        Oa0[of] = mfma16(pa0[cf], vf, Oa0[of]);
        Oa1[of] = mfma16(pa1[cf], vf, Oa1[of]);
      }
    }
  }

  int b = bh >> 4, h = bh & 15;
  float il0 = 1.0f / l0, il1 = 1.0f / l1;
#pragma unroll
  for (int j = 0; j < 4; ++j) {
    float v0 = __shfl(il0, lg * 4 + j);
    float v1 = __shfl(il1, lg * 4 + j);
    int r0 = q0 + wid * 32 + 4 * lg + j;
#pragma unroll
    for (int of = 0; of < 5; ++of) {
      int d = of * 16 + lr;
      if (d < 72) {
        AO[(size_t)(b * 2048 + r0) * 1152 + h * 72 + d]      = f2b_bits(Oa0[of][j] * v0);
        AO[(size_t)(b * 2048 + r0 + 16) * 1152 + h * 72 + d] = f2b_bits(Oa1[of][j] * v1);
      }
    }
  }
}

// ---------------- launch -----------------------------------------------------
extern "C" void kernel_launch(void* const* d_in, const int* in_sizes, int n_in,
                              void* d_out, int out_size, void* d_ws, size_t ws_size,
                              hipStream_t stream) {
  const float* hs = (const float*)d_in[0];
  const float* Wq = (const float*)d_in[1];
  const float* bq = (const float*)d_in[2];
  const float* Wk = (const float*)d_in[3];
  const float* bk = (const float*)d_in[4];
  const float* Wv = (const float*)d_in[5];
  const float* bv = (const float*)d_in[6];
  const float* Wo = (const float*)d_in[7];
  const float* bo = (const float*)d_in[8];
  float* out = (float*)d_out;

  char* w = (char*)d_ws;
  u16* xb  = (u16*)w; w += 9437184;    // x bf16 [4096][1152]; later reused as AO
  u16* wqb = (u16*)w; w += 2654208;
  u16* wkb = (u16*)w; w += 2654208;
  u16* wvb = (u16*)w; w += 2654208;
  u16* wob = (u16*)w; w += 2654208;
  u16* qkv = (u16*)w; w += 28311552;   // [4096][3456]
  u16* Qr  = (u16*)w; w += 10485760;   // [32][2048][80]
  u16* Kr  = (u16*)w; w += 10485760;
  u16* Vt  = (u16*)w; w += 10485760;   // [32][80][2048]
  u16* AO  = xb;                       // attn out [4096][1152], aliases xb

  convert_kernel<<<9792, 256, 0, stream>>>(hs, Wq, Wk, Wv, Wo, xb, wqb, wkb, wvb, wob);
  gemm_kernel<0><<<864, 256, 0, stream>>>(xb, wqb, wkb, wvb, bq, bk, bv, qkv, nullptr, 27);
  rope_kernel<<<512, 256, 0, stream>>>(qkv, Qr, Kr);
  vtrans_kernel<<<512, 256, 0, stream>>>(qkv, Vt);
  attn_kernel<<<512, 256, 0, stream>>>(Qr, Kr, Vt, AO);
  gemm_kernel<1><<<288, 256, 0, stream>>>(AO, wob, nullptr, nullptr, bo, nullptr, nullptr,
                                          nullptr, out, 9);
}